// Round 1
// baseline (4009.188 us; speedup 1.0000x reference)
//
#include <hip/hip_runtime.h>
#include <stdint.h>

// LSTM forward, B=128 T=512 F=256 H=512, Keras gate order i,f,g,o.
//  kernel lstm_xz : xz[B*T,2048] = x @ kernel + bias  (split-bf16 MFMA, fp16 output in ws)
//  kernel lstm_rec: persistent scan. R1 restructure:
//    - Grid 128 = 8 row-groups x 16 col-blocks (was 512 = 8x64). Each block holds its
//      full R slice [512 x 128] bf16 = 128 KB in LDS (1 block/CU; 128 blocks co-resident).
//    - Per-wave gate-interleaved cols: wave owns 8 h-cols as two 16-col MFMA tiles
//      [i|f] and [g|o]; elementwise is wave-local via shfl_xor(8). zbuf + one
//      __syncthreads deleted; ew runs on all 4 waves.
//    - Barrier: per-WAVE flag array (64 flags/group), each wave stores flag=t+1 after
//      its own s_waitcnt vmcnt(0) (sc1 h-stores at coherence point). Consumers poll all
//      64 flags with ONE vector sc1 load + __all. No contended fetch_add, no gen word.
//    - LDS XOR-swizzle (k ^ ((row&7)<<3) shorts) on R and h tiles: conflict-free
//      ds_read_b128 without padding.
//    - xz[t+1] prefetch issued before GEMM (latency hides under MFMA+ew).
// ws layout: [0, 256MB) xz fp16 | hbuf 2x128x512 bf16 (256KB) | barrier 2KB

#define Bb 128
#define Tt 512
#define Ff 256
#define Hh 512
#define G4 2048

typedef __attribute__((ext_vector_type(8))) short short8;
typedef __attribute__((ext_vector_type(4))) float floatx4;

__device__ __forceinline__ unsigned short f2bf(float f) {
    unsigned u = __float_as_uint(f);
    return (unsigned short)((u + 0x7FFFu + ((u >> 16) & 1u)) >> 16);
}
__device__ __forceinline__ float bf2f(unsigned short h) {
    return __uint_as_float(((unsigned)h) << 16);
}
__device__ __forceinline__ float sigm(float x) { return 1.f / (1.f + __expf(-x)); }
__device__ __forceinline__ float tanh_f(float x) {
    float e = __expf(-2.f * fabsf(x));
    return copysignf((1.f - e) / (1.f + e), x);
}

// ---------------------------------------------------------------------------
// Kernel A: xz = x @ w + bias, stored fp16. Split-bf16 (x=hi+lo) for accuracy.
// 128x128 tile / block, BK=32 (orig k), K=256. Grid 8192 blocks. (unchanged)
// ---------------------------------------------------------------------------
__global__ __launch_bounds__(256, 2) void lstm_xz(
    const float* __restrict__ x, const float* __restrict__ w,
    const float* __restrict__ bias, _Float16* __restrict__ xzh)
{
    __shared__ unsigned short Ahi[128 * 40];
    __shared__ unsigned short Alo[128 * 40];
    __shared__ unsigned short Wt [128 * 40];

    const int tid = threadIdx.x;
    int idx = blockIdx.x;
    int xcd = idx & 7;
    int chunk = idx >> 3;
    int msup = chunk >> 7;
    int s = chunk & 127;
    int nt = s >> 3;
    int mi0 = s & 7;
    int mt = xcd * 64 + msup * 8 + mi0;
    const int m0 = mt << 7;
    const int n0 = nt << 7;

    const int lane = tid & 63;
    const int wv = tid >> 6;
    const int wm = wv >> 1, wn = wv & 1;
    const int cB = lane & 15, kgrp = lane >> 4;

    floatx4 acc[4][4];
#pragma unroll
    for (int i = 0; i < 4; ++i)
#pragma unroll
        for (int j = 0; j < 4; ++j) acc[i][j] = (floatx4){0.f, 0.f, 0.f, 0.f};

    float bv[4];
#pragma unroll
    for (int ni = 0; ni < 4; ++ni) bv[ni] = bias[n0 + wn * 64 + ni * 16 + cB];

    for (int it = 0; it < 8; ++it) {
        const int k0 = it * 32;
#pragma unroll
        for (int sw = 0; sw < 4; ++sw) {
            int e = sw * 256 + tid;
            int row = e >> 3, kq = e & 7;
            float4 v = *((const float4*)(x + (size_t)(m0 + row) * Ff + k0) + kq);
            unsigned short h0 = f2bf(v.x), h1 = f2bf(v.y), h2 = f2bf(v.z), h3 = f2bf(v.w);
            unsigned short l0 = f2bf(v.x - bf2f(h0)), l1 = f2bf(v.y - bf2f(h1));
            unsigned short l2 = f2bf(v.z - bf2f(h2)), l3 = f2bf(v.w - bf2f(h3));
            uint2 ph, pl;
            ph.x = (unsigned)h0 | ((unsigned)h1 << 16); ph.y = (unsigned)h2 | ((unsigned)h3 << 16);
            pl.x = (unsigned)l0 | ((unsigned)l1 << 16); pl.y = (unsigned)l2 | ((unsigned)l3 << 16);
            *(uint2*)(&Ahi[row * 40 + kq * 4]) = ph;
            *(uint2*)(&Alo[row * 40 + kq * 4]) = pl;
        }
#pragma unroll
        for (int sw = 0; sw < 4; ++sw) {
            int e = sw * 256 + tid;
            int kr = e >> 5, nq = e & 31;
            float4 v = *((const float4*)(w + (size_t)(k0 + kr) * G4 + n0) + nq);
            int nb = nq * 4;
            Wt[(nb + 0) * 40 + kr] = f2bf(v.x);
            Wt[(nb + 1) * 40 + kr] = f2bf(v.y);
            Wt[(nb + 2) * 40 + kr] = f2bf(v.z);
            Wt[(nb + 3) * 40 + kr] = f2bf(v.w);
        }
        __syncthreads();

        short8 bfr[4];
#pragma unroll
        for (int ni = 0; ni < 4; ++ni)
            bfr[ni] = *(const short8*)(&Wt[(wn * 64 + ni * 16 + cB) * 40 + kgrp * 8]);
#pragma unroll
        for (int mi = 0; mi < 4; ++mi) {
            short8 ah = *(const short8*)(&Ahi[(wm * 64 + mi * 16 + cB) * 40 + kgrp * 8]);
            short8 al = *(const short8*)(&Alo[(wm * 64 + mi * 16 + cB) * 40 + kgrp * 8]);
#pragma unroll
            for (int ni = 0; ni < 4; ++ni) {
                acc[mi][ni] = __builtin_amdgcn_mfma_f32_16x16x32_bf16(ah, bfr[ni], acc[mi][ni], 0, 0, 0);
                acc[mi][ni] = __builtin_amdgcn_mfma_f32_16x16x32_bf16(al, bfr[ni], acc[mi][ni], 0, 0, 0);
            }
        }
        __syncthreads();
    }
#pragma unroll
    for (int mi = 0; mi < 4; ++mi)
#pragma unroll
        for (int ni = 0; ni < 4; ++ni) {
            int rowb = m0 + wm * 64 + mi * 16 + kgrp * 4;
            int col = n0 + wn * 64 + ni * 16 + cB;
#pragma unroll
            for (int rr = 0; rr < 4; ++rr)
                xzh[(size_t)(rowb + rr) * G4 + col] = (_Float16)(acc[mi][ni][rr] + bv[ni]);
        }
}

// ---------------------------------------------------------------------------
// Kernel R: persistent scan, 128 blocks = 8 row-groups x 16 col-blocks.
// Block: 256 thr / 4 waves; wave w owns h cols [cb*32 + w*8, +8) (x 4 gates = 32 n).
// R slice [n=128][k=512] bf16 in LDS (XOR-swizzled), h tile [16][512] staged per step.
// ---------------------------------------------------------------------------
__global__ __launch_bounds__(256, 1) void lstm_rec(
    const _Float16* __restrict__ xzh, const float* __restrict__ rk,
    unsigned* __restrict__ hbuf_u, unsigned* __restrict__ bar,
    float* __restrict__ out)
{
    __shared__ unsigned short Rlds[128 * 512];   // 128 KB, [n][k] swizzled
    __shared__ unsigned short hlds[16 * 512];    // 16 KB,  [row][k] swizzled

    const int tid = threadIdx.x;
    const int idx = blockIdx.x;
    const int rg = idx & 7;          // row group (round-robin -> same-XCD heuristic, perf only)
    const int cb = idx >> 3;         // 0..15 col block
    const int b0 = rg * 16;
    const int hc0 = cb * 32;

    const int lane = tid & 63;
    const int wv = tid >> 6;
    const int cB = lane & 15, kgrp = lane >> 4;
    const int hcw = hc0 + wv * 8;    // wave's 8 h cols
    const int c7 = cB & 7;
    const int col = hcw + c7;        // this lane's h col (duplicated in lane^8)
    const bool hi = (cB & 8) != 0;

    // ---- preload R slice into LDS, bf16, XOR-swizzled: elem (n,k) at k^((n&7)*8) ----
    // n (0..127): w=n>>5, loc=n&31, gate=((loc>>4)<<1)|((loc>>3)&1), hcol=loc&7
    for (int e = tid; e < 64 * 512; e += 256) {
        int p = e & 63, k = e >> 6;
        int n0 = 2 * p;
        int loc = n0 & 31, w = n0 >> 5;
        int gate = ((loc >> 4) << 1) | ((loc >> 3) & 1);
        int gcol = gate * Hh + hc0 + w * 8 + (loc & 7);
        float2 v = *(const float2*)(rk + (size_t)k * G4 + gcol);
        Rlds[n0 * 512 + (k ^ ((n0 & 7) << 3))] = f2bf(v.x);
        Rlds[(n0 + 1) * 512 + (k ^ (((n0 + 1) & 7) << 3))] = f2bf(v.y);
    }

    unsigned* hb0 = hbuf_u;
    unsigned* hb1 = hbuf_u + (size_t)Bb * Hh / 2;
    unsigned* flags = bar + rg * 64;          // 64 per-wave flags per group

    float creg[4] = {0.f, 0.f, 0.f, 0.f};
    float xzr[16];                            // [gate*4 + reg(row)]
    const unsigned* xz_u = (const unsigned*)xzh;

    // initial xz for t=0: rows b0 + kgrp*4 + r, col pair (col&~1)
#pragma unroll
    for (int g = 0; g < 4; ++g)
#pragma unroll
        for (int r = 0; r < 4; ++r) {
            size_t b = (size_t)(b0 + kgrp * 4 + r);
            unsigned v = xz_u[((b * Tt + 0) * G4 + (size_t)g * Hh + (col & ~1)) >> 1];
            xzr[g * 4 + r] = (float)__builtin_bit_cast(_Float16,
                (unsigned short)((col & 1) ? (v >> 16) : (v & 0xffffu)));
        }
    __syncthreads();  // Rlds ready

    unsigned* hlds_u = (unsigned*)hlds;

    for (int t = 0; t < Tt; ++t) {
        const unsigned* hrd = (t & 1) ? hb1 : hb0;
        unsigned* hwr = (t & 1) ? hb0 : hb1;

        // poll: all 64 group flags >= t (one vector sc1 load; skip own block's 4 flags —
        // own stores are visible after our own vmcnt(0)+barrier last step)
        if (t > 0) {
            const unsigned tgt = (unsigned)t;
            for (;;) {
                unsigned f = tgt;
                if ((lane >> 2) != cb)
                    f = __hip_atomic_load(flags + lane, __ATOMIC_RELAXED,
                                          __HIP_MEMORY_SCOPE_AGENT);
                if (__all(f >= tgt)) break;
                __builtin_amdgcn_s_sleep(1);
            }
        }

        // stage h tile: 16 rows x 256 dwords, swizzled (dword d -> d ^ ((row&7)*4))
        {
            const unsigned* hbr = hrd + (size_t)b0 * 256;
#pragma unroll
            for (int i = 0; i < 16; ++i) {
                unsigned v = __hip_atomic_load(hbr + i * 256 + tid, __ATOMIC_RELAXED,
                                               __HIP_MEMORY_SCOPE_AGENT);
                hlds_u[i * 256 + (tid ^ ((i & 7) << 2))] = v;
            }
        }
        __syncthreads();

        // prefetch next-step xz early: HBM latency hides under GEMM + ew
        unsigned pf[16];
        if (t < Tt - 1) {
#pragma unroll
            for (int g = 0; g < 4; ++g)
#pragma unroll
                for (int r = 0; r < 4; ++r) {
                    size_t b = (size_t)(b0 + kgrp * 4 + r);
                    pf[g * 4 + r] = xz_u[((b * Tt + (size_t)(t + 1)) * G4
                                          + (size_t)g * Hh + (col & ~1)) >> 1];
                }
        }

        // GEMM: per-wave 2 acc tiles over full K=512: tile0=[i|f], tile1=[g|o]
        floatx4 acc0 = (floatx4){0.f, 0.f, 0.f, 0.f};
        floatx4 acc1 = (floatx4){0.f, 0.f, 0.f, 0.f};
        {
            const int nb = wv * 32;
            const int swz = (cB & 7) << 3;
#pragma unroll
            for (int kk = 0; kk < 16; ++kk) {
                int kb = (kk * 32 + kgrp * 8) ^ swz;
                short8 a   = *(const short8*)&hlds[cB * 512 + kb];
                short8 bb0 = *(const short8*)&Rlds[(nb + cB) * 512 + kb];
                short8 bb1 = *(const short8*)&Rlds[(nb + 16 + cB) * 512 + kb];
                acc0 = __builtin_amdgcn_mfma_f32_16x16x32_bf16(a, bb0, acc0, 0, 0, 0);
                acc1 = __builtin_amdgcn_mfma_f32_16x16x32_bf16(a, bb1, acc1, 0, 0, 0);
            }
        }

        // elementwise, in-register. C layout: col=lane&15, row=kgrp*4+reg.
        // tile0 cols: cB<8 -> gate i col c7, cB>=8 -> gate f col c7. shfl_xor(8) pairs them.
        float hv[4];
#pragma unroll
        for (int r = 0; r < 4; ++r) {
            float a0 = acc0[r], a1 = acc1[r];
            float a0x = __shfl_xor(a0, 8);
            float a1x = __shfl_xor(a1, 8);
            float zi = (hi ? a0x : a0) + xzr[0 * 4 + r];
            float zf = (hi ? a0 : a0x) + xzr[1 * 4 + r];
            float zg = (hi ? a1x : a1) + xzr[2 * 4 + r];
            float zo = (hi ? a1 : a1x) + xzr[3 * 4 + r];
            creg[r] = sigm(zf) * creg[r] + sigm(zi) * tanh_f(zg);
            hv[r] = sigm(zo) * tanh_f(creg[r]);
        }

        // stores: even cB<8 lanes own col pairs (col, col+1); neighbor via shfl_xor(1)
#pragma unroll
        for (int r = 0; r < 4; ++r) {
            float hn = __shfl_xor(hv[r], 1);
            size_t b = (size_t)(b0 + kgrp * 4 + r);
            if (!hi && !(cB & 1)) {
                *(float2*)(out + (b * Tt + (size_t)t) * Hh + col) = make_float2(hv[r], hn);
                unsigned hp = (unsigned)f2bf(hv[r]) | ((unsigned)f2bf(hn) << 16);
                __hip_atomic_store(hwr + b * 256 + (col >> 1), hp,
                                   __ATOMIC_RELAXED, __HIP_MEMORY_SCOPE_AGENT);
            }
        }

        if (t == Tt - 1) {
            float* hl = out + (size_t)Bb * Tt * Hh;
            float* cl = hl + (size_t)Bb * Hh;
#pragma unroll
            for (int r = 0; r < 4; ++r) {
                float hn = __shfl_xor(hv[r], 1);
                float cn = __shfl_xor(creg[r], 1);
                size_t b = (size_t)(b0 + kgrp * 4 + r);
                if (!hi && !(cB & 1)) {
                    *(float2*)(hl + b * Hh + col) = make_float2(hv[r], hn);
                    *(float2*)(cl + b * Hh + col) = make_float2(creg[r], cn);
                }
            }
            break;
        }

        // consume prefetched xz into xzr for next step
#pragma unroll
        for (int i = 0; i < 16; ++i)
            xzr[i] = (float)__builtin_bit_cast(_Float16,
                (unsigned short)((col & 1) ? (pf[i] >> 16) : (pf[i] & 0xffffu)));

        // per-wave signal: own h sc1-stores at device coherence point after vmcnt(0);
        // flag store ordered after it in program order (same wave).
        asm volatile("s_waitcnt vmcnt(0)" ::: "memory");
        if (lane == 0)
            __hip_atomic_store(flags + cb * 4 + wv, (unsigned)(t + 1),
                               __ATOMIC_RELAXED, __HIP_MEMORY_SCOPE_AGENT);
        __syncthreads();   // protects hlds (reads done before next-step restage)
    }
}

// ---------------------------------------------------------------------------
extern "C" void kernel_launch(void* const* d_in, const int* in_sizes, int n_in,
                              void* d_out, int out_size, void* d_ws, size_t ws_size,
                              hipStream_t stream) {
    (void)in_sizes; (void)n_in; (void)out_size; (void)ws_size;
    const float* x    = (const float*)d_in[0];
    const float* w    = (const float*)d_in[1];
    const float* rk   = (const float*)d_in[2];
    const float* bias = (const float*)d_in[3];
    float* out = (float*)d_out;

    char* ws = (char*)d_ws;
    const size_t XZ_BYTES   = (size_t)Bb * Tt * G4 * sizeof(_Float16);      // 268,435,456
    const size_t HBUF_BYTES = (size_t)2 * Bb * Hh * sizeof(unsigned short); // 262,144
    const size_t BAR_BYTES  = 2048;

    _Float16* xzh = (_Float16*)ws;
    unsigned* hbuf = (unsigned*)(ws + XZ_BYTES);
    unsigned* bar = (unsigned*)(ws + XZ_BYTES + HBUF_BYTES);

    hipMemsetAsync(ws + XZ_BYTES, 0, HBUF_BYTES + BAR_BYTES, stream);

    lstm_xz<<<dim3(8192), dim3(256), 0, stream>>>(x, w, bias, xzh);
    lstm_rec<<<dim3(128), dim3(256), 0, stream>>>(xzh, rk, hbuf, bar, out);
}

// Round 2
// 2525.716 us; speedup vs baseline: 1.5873x; 1.5873x over previous
//
#include <hip/hip_runtime.h>
#include <stdint.h>

// LSTM forward, B=128 T=512 F=256 H=512, Keras gate order i,f,g,o.
//  kernel lstm_xz : xz[B*T,2048] = x @ kernel + bias  (split-bf16 MFMA, fp16 output in ws)
//  kernel lstm_rec: persistent scan. R2: attack the serialized h-stage.
//    - R1 post-mortem: 16 __hip_atomic_load each feeding a dependent ds_write =>
//      backend serializes (load; waitcnt; write) x16 = ~11k cyc/step of LLC round trips.
//      Replaced with 4x inline-asm global_load_dwordx4 sc0 sc1 (pipelined), ONE
//      s_waitcnt vmcnt(0), then 4x ds_write_b128. ~800 cyc instead of ~11k.
//    - xz[t+1] prefetch issued BEFORE the flag poll (poll duration hides HBM latency).
//    - Poll spin without s_sleep (lower discovery latency).
//    - out stores AFTER vmcnt(0)+flag signal (HBM store ack off the producer chain).
//    - Last step: skip hbuf stores + flag entirely.
// ws layout: [0, 256MB) xz fp16 | hbuf 2x128x512 bf16 (256KB) | barrier 2KB

#define Bb 128
#define Tt 512
#define Ff 256
#define Hh 512
#define G4 2048

typedef __attribute__((ext_vector_type(8))) short short8;
typedef __attribute__((ext_vector_type(4))) float floatx4;
typedef __attribute__((ext_vector_type(4))) unsigned int uint4v;

__device__ __forceinline__ unsigned short f2bf(float f) {
    unsigned u = __float_as_uint(f);
    return (unsigned short)((u + 0x7FFFu + ((u >> 16) & 1u)) >> 16);
}
__device__ __forceinline__ float bf2f(unsigned short h) {
    return __uint_as_float(((unsigned)h) << 16);
}
__device__ __forceinline__ float sigm(float x) { return 1.f / (1.f + __expf(-x)); }
__device__ __forceinline__ float tanh_f(float x) {
    float e = __expf(-2.f * fabsf(x));
    return copysignf((1.f - e) / (1.f + e), x);
}

// ---------------------------------------------------------------------------
// Kernel A: xz = x @ w + bias, stored fp16. Split-bf16 (x=hi+lo) for accuracy.
// 128x128 tile / block, BK=32 (orig k), K=256. Grid 8192 blocks. (unchanged)
// ---------------------------------------------------------------------------
__global__ __launch_bounds__(256, 2) void lstm_xz(
    const float* __restrict__ x, const float* __restrict__ w,
    const float* __restrict__ bias, _Float16* __restrict__ xzh)
{
    __shared__ unsigned short Ahi[128 * 40];
    __shared__ unsigned short Alo[128 * 40];
    __shared__ unsigned short Wt [128 * 40];

    const int tid = threadIdx.x;
    int idx = blockIdx.x;
    int xcd = idx & 7;
    int chunk = idx >> 3;
    int msup = chunk >> 7;
    int s = chunk & 127;
    int nt = s >> 3;
    int mi0 = s & 7;
    int mt = xcd * 64 + msup * 8 + mi0;
    const int m0 = mt << 7;
    const int n0 = nt << 7;

    const int lane = tid & 63;
    const int wv = tid >> 6;
    const int wm = wv >> 1, wn = wv & 1;
    const int cB = lane & 15, kgrp = lane >> 4;

    floatx4 acc[4][4];
#pragma unroll
    for (int i = 0; i < 4; ++i)
#pragma unroll
        for (int j = 0; j < 4; ++j) acc[i][j] = (floatx4){0.f, 0.f, 0.f, 0.f};

    float bv[4];
#pragma unroll
    for (int ni = 0; ni < 4; ++ni) bv[ni] = bias[n0 + wn * 64 + ni * 16 + cB];

    for (int it = 0; it < 8; ++it) {
        const int k0 = it * 32;
#pragma unroll
        for (int sw = 0; sw < 4; ++sw) {
            int e = sw * 256 + tid;
            int row = e >> 3, kq = e & 7;
            float4 v = *((const float4*)(x + (size_t)(m0 + row) * Ff + k0) + kq);
            unsigned short h0 = f2bf(v.x), h1 = f2bf(v.y), h2 = f2bf(v.z), h3 = f2bf(v.w);
            unsigned short l0 = f2bf(v.x - bf2f(h0)), l1 = f2bf(v.y - bf2f(h1));
            unsigned short l2 = f2bf(v.z - bf2f(h2)), l3 = f2bf(v.w - bf2f(h3));
            uint2 ph, pl;
            ph.x = (unsigned)h0 | ((unsigned)h1 << 16); ph.y = (unsigned)h2 | ((unsigned)h3 << 16);
            pl.x = (unsigned)l0 | ((unsigned)l1 << 16); pl.y = (unsigned)l2 | ((unsigned)l3 << 16);
            *(uint2*)(&Ahi[row * 40 + kq * 4]) = ph;
            *(uint2*)(&Alo[row * 40 + kq * 4]) = pl;
        }
#pragma unroll
        for (int sw = 0; sw < 4; ++sw) {
            int e = sw * 256 + tid;
            int kr = e >> 5, nq = e & 31;
            float4 v = *((const float4*)(w + (size_t)(k0 + kr) * G4 + n0) + nq);
            int nb = nq * 4;
            Wt[(nb + 0) * 40 + kr] = f2bf(v.x);
            Wt[(nb + 1) * 40 + kr] = f2bf(v.y);
            Wt[(nb + 2) * 40 + kr] = f2bf(v.z);
            Wt[(nb + 3) * 40 + kr] = f2bf(v.w);
        }
        __syncthreads();

        short8 bfr[4];
#pragma unroll
        for (int ni = 0; ni < 4; ++ni)
            bfr[ni] = *(const short8*)(&Wt[(wn * 64 + ni * 16 + cB) * 40 + kgrp * 8]);
#pragma unroll
        for (int mi = 0; mi < 4; ++mi) {
            short8 ah = *(const short8*)(&Ahi[(wm * 64 + mi * 16 + cB) * 40 + kgrp * 8]);
            short8 al = *(const short8*)(&Alo[(wm * 64 + mi * 16 + cB) * 40 + kgrp * 8]);
#pragma unroll
            for (int ni = 0; ni < 4; ++ni) {
                acc[mi][ni] = __builtin_amdgcn_mfma_f32_16x16x32_bf16(ah, bfr[ni], acc[mi][ni], 0, 0, 0);
                acc[mi][ni] = __builtin_amdgcn_mfma_f32_16x16x32_bf16(al, bfr[ni], acc[mi][ni], 0, 0, 0);
            }
        }
        __syncthreads();
    }
#pragma unroll
    for (int mi = 0; mi < 4; ++mi)
#pragma unroll
        for (int ni = 0; ni < 4; ++ni) {
            int rowb = m0 + wm * 64 + mi * 16 + kgrp * 4;
            int col = n0 + wn * 64 + ni * 16 + cB;
#pragma unroll
            for (int rr = 0; rr < 4; ++rr)
                xzh[(size_t)(rowb + rr) * G4 + col] = (_Float16)(acc[mi][ni][rr] + bv[ni]);
        }
}

// ---------------------------------------------------------------------------
// Kernel R: persistent scan, 128 blocks = 8 row-groups x 16 col-blocks.
// Block: 256 thr / 4 waves; wave w owns h cols [cb*32 + w*8, +8) (x 4 gates = 32 n).
// R slice [n=128][k=512] bf16 in LDS (XOR-swizzled), h tile [16][512] staged per step.
// ---------------------------------------------------------------------------
__global__ __launch_bounds__(256, 1) void lstm_rec(
    const _Float16* __restrict__ xzh, const float* __restrict__ rk,
    unsigned* __restrict__ hbuf_u, unsigned* __restrict__ bar,
    float* __restrict__ out)
{
    __shared__ unsigned short Rlds[128 * 512];   // 128 KB, [n][k] swizzled
    __shared__ unsigned short hlds[16 * 512];    // 16 KB,  [row][k] swizzled

    const int tid = threadIdx.x;
    const int idx = blockIdx.x;
    const int rg = idx & 7;          // row group
    const int cb = idx >> 3;         // 0..15 col block
    const int b0 = rg * 16;
    const int hc0 = cb * 32;

    const int lane = tid & 63;
    const int wv = tid >> 6;
    const int cB = lane & 15, kgrp = lane >> 4;
    const int hcw = hc0 + wv * 8;    // wave's 8 h cols
    const int c7 = cB & 7;
    const int col = hcw + c7;        // this lane's h col (duplicated in lane^8)
    const bool hi = (cB & 8) != 0;

    // ---- preload R slice into LDS, bf16, XOR-swizzled: elem (n,k) at k^((n&7)*8) ----
    for (int e = tid; e < 64 * 512; e += 256) {
        int p = e & 63, k = e >> 6;
        int n0 = 2 * p;
        int loc = n0 & 31, w = n0 >> 5;
        int gate = ((loc >> 4) << 1) | ((loc >> 3) & 1);
        int gcol = gate * Hh + hc0 + w * 8 + (loc & 7);
        float2 v = *(const float2*)(rk + (size_t)k * G4 + gcol);
        Rlds[n0 * 512 + (k ^ ((n0 & 7) << 3))] = f2bf(v.x);
        Rlds[(n0 + 1) * 512 + (k ^ (((n0 + 1) & 7) << 3))] = f2bf(v.y);
    }

    unsigned* hb0 = hbuf_u;
    unsigned* hb1 = hbuf_u + (size_t)Bb * Hh / 2;
    unsigned* flags = bar + rg * 64;          // 64 per-wave flags per group

    float creg[4] = {0.f, 0.f, 0.f, 0.f};
    float xzr[16];                            // [gate*4 + reg(row)]
    const unsigned* xz_u = (const unsigned*)xzh;

    // per-(g,r) running xz pointers
    const unsigned* pxz[16];
#pragma unroll
    for (int g = 0; g < 4; ++g)
#pragma unroll
        for (int r = 0; r < 4; ++r) {
            size_t b = (size_t)(b0 + kgrp * 4 + r);
            pxz[g * 4 + r] = xz_u + ((b * Tt) * G4 + (size_t)g * Hh + (col & ~1)) / 2;
        }

    // initial xz for t=0
#pragma unroll
    for (int i = 0; i < 16; ++i) {
        unsigned v = pxz[i][0];
        xzr[i] = (float)__builtin_bit_cast(_Float16,
            (unsigned short)((col & 1) ? (v >> 16) : (v & 0xffffu)));
    }
    __syncthreads();  // Rlds ready

    unsigned* hlds_u = (unsigned*)hlds;
    const int skip_lo = cb * 4, skip_hi = cb * 4 + 3;

    for (int t = 0; t < Tt; ++t) {
        const bool last = (t == Tt - 1);
        const unsigned* hrd = (t & 1) ? hb1 : hb0;
        unsigned* hwr = (t & 1) ? hb0 : hb1;

        // 1. prefetch next-step xz BEFORE the poll: poll duration hides HBM latency
        unsigned pf[16];
        if (!last) {
#pragma unroll
            for (int i = 0; i < 16; ++i) pf[i] = pxz[i][(size_t)(t + 1) * (G4 / 2)];
        }

        // 2. poll: all 64 group flags >= t (one vector sc1 load / iter; no sleep)
        if (t > 0) {
            const unsigned tgt = (unsigned)t;
            for (;;) {
                unsigned f = tgt;
                if (lane < skip_lo || lane > skip_hi)
                    f = __hip_atomic_load(flags + lane, __ATOMIC_RELAXED,
                                          __HIP_MEMORY_SCOPE_AGENT);
                if (__all(f >= tgt)) break;
            }
        }

        // 3. stage h tile: per thread 4x dwordx4 sc0|sc1 loads (PIPELINED, inline asm),
        //    ONE vmcnt(0), then 4x ds_write_b128. Wave wv stages rows wv+4s.
        //    LDS swizzle at 4-dword chunks: chunk j -> j ^ (row&7); matches GEMM read.
        {
            const unsigned* hbr = hrd + (size_t)b0 * 256;
            const unsigned* p0 = hbr + (wv + 0) * 256 + 4 * lane;
            const unsigned* p1 = hbr + (wv + 4) * 256 + 4 * lane;
            const unsigned* p2 = hbr + (wv + 8) * 256 + 4 * lane;
            const unsigned* p3 = hbr + (wv + 12) * 256 + 4 * lane;
            uint4v t0, t1, t2, t3;
            asm volatile("global_load_dwordx4 %0, %1, off sc0 sc1" : "=v"(t0) : "v"(p0) : "memory");
            asm volatile("global_load_dwordx4 %0, %1, off sc0 sc1" : "=v"(t1) : "v"(p1) : "memory");
            asm volatile("global_load_dwordx4 %0, %1, off sc0 sc1" : "=v"(t2) : "v"(p2) : "memory");
            asm volatile("global_load_dwordx4 %0, %1, off sc0 sc1" : "=v"(t3) : "v"(p3) : "memory");
            asm volatile("s_waitcnt vmcnt(0)" ::: "memory");
            __builtin_amdgcn_sched_barrier(0);
            *(uint4v*)(hlds_u + (wv + 0) * 256 + 4 * (lane ^ ((wv + 0) & 7))) = t0;
            *(uint4v*)(hlds_u + (wv + 4) * 256 + 4 * (lane ^ ((wv + 4) & 7))) = t1;
            *(uint4v*)(hlds_u + (wv + 8) * 256 + 4 * (lane ^ ((wv + 8) & 7))) = t2;
            *(uint4v*)(hlds_u + (wv + 12) * 256 + 4 * (lane ^ ((wv + 12) & 7))) = t3;
        }
        __syncthreads();

        // 4. GEMM: per-wave 2 acc tiles over full K=512: tile0=[i|f], tile1=[g|o]
        floatx4 acc0 = (floatx4){0.f, 0.f, 0.f, 0.f};
        floatx4 acc1 = (floatx4){0.f, 0.f, 0.f, 0.f};
        {
            const int nb = wv * 32;
            const int swz = (cB & 7) << 3;
#pragma unroll
            for (int kk = 0; kk < 16; ++kk) {
                int kb = (kk * 32 + kgrp * 8) ^ swz;
                short8 a   = *(const short8*)&hlds[cB * 512 + kb];
                short8 bb0 = *(const short8*)&Rlds[(nb + cB) * 512 + kb];
                short8 bb1 = *(const short8*)&Rlds[(nb + 16 + cB) * 512 + kb];
                acc0 = __builtin_amdgcn_mfma_f32_16x16x32_bf16(a, bb0, acc0, 0, 0, 0);
                acc1 = __builtin_amdgcn_mfma_f32_16x16x32_bf16(a, bb1, acc1, 0, 0, 0);
            }
        }

        // 5. elementwise, in-register. C layout: col=lane&15, row=kgrp*4+reg.
        float hv[4];
#pragma unroll
        for (int r = 0; r < 4; ++r) {
            float a0 = acc0[r], a1 = acc1[r];
            float a0x = __shfl_xor(a0, 8);
            float a1x = __shfl_xor(a1, 8);
            float zi = (hi ? a0x : a0) + xzr[0 * 4 + r];
            float zf = (hi ? a0 : a0x) + xzr[1 * 4 + r];
            float zg = (hi ? a1x : a1) + xzr[2 * 4 + r];
            float zo = (hi ? a1 : a1x) + xzr[3 * 4 + r];
            creg[r] = sigm(zf) * creg[r] + sigm(zi) * tanh_f(zg);
            hv[r] = sigm(zo) * tanh_f(creg[r]);
        }

        float hn[4];
#pragma unroll
        for (int r = 0; r < 4; ++r) hn[r] = __shfl_xor(hv[r], 1);
        const bool ew = (!hi && !(cB & 1));

        if (!last) {
            // 6. h exchange FIRST: sc1 stores -> vmcnt(0) -> flag signal
#pragma unroll
            for (int r = 0; r < 4; ++r) {
                if (ew) {
                    size_t b = (size_t)(b0 + kgrp * 4 + r);
                    unsigned hp = (unsigned)f2bf(hv[r]) | ((unsigned)f2bf(hn[r]) << 16);
                    __hip_atomic_store(hwr + b * 256 + (col >> 1), hp,
                                       __ATOMIC_RELAXED, __HIP_MEMORY_SCOPE_AGENT);
                }
            }
            asm volatile("s_waitcnt vmcnt(0)" ::: "memory");
            if (lane == 0)
                __hip_atomic_store(flags + cb * 4 + wv, (unsigned)(t + 1),
                                   __ATOMIC_RELAXED, __HIP_MEMORY_SCOPE_AGENT);
        }

        // 7. output stores (cached; off the producer->consumer chain)
#pragma unroll
        for (int r = 0; r < 4; ++r) {
            if (ew) {
                size_t b = (size_t)(b0 + kgrp * 4 + r);
                *(float2*)(out + (b * Tt + (size_t)t) * Hh + col) = make_float2(hv[r], hn[r]);
            }
        }

        if (last) {
            float* hl = out + (size_t)Bb * Tt * Hh;
            float* cl = hl + (size_t)Bb * Hh;
#pragma unroll
            for (int r = 0; r < 4; ++r) {
                float cn = __shfl_xor(creg[r], 1);
                if (ew) {
                    size_t b = (size_t)(b0 + kgrp * 4 + r);
                    *(float2*)(hl + b * Hh + col) = make_float2(hv[r], hn[r]);
                    *(float2*)(cl + b * Hh + col) = make_float2(creg[r], cn);
                }
            }
            break;
        }

        // 8. consume prefetched xz into xzr for next step
#pragma unroll
        for (int i = 0; i < 16; ++i)
            xzr[i] = (float)__builtin_bit_cast(_Float16,
                (unsigned short)((col & 1) ? (pf[i] >> 16) : (pf[i] & 0xffffu)));

        __syncthreads();   // protects hlds (all GEMM reads done before next restage)
    }
}

// ---------------------------------------------------------------------------
extern "C" void kernel_launch(void* const* d_in, const int* in_sizes, int n_in,
                              void* d_out, int out_size, void* d_ws, size_t ws_size,
                              hipStream_t stream) {
    (void)in_sizes; (void)n_in; (void)out_size; (void)ws_size;
    const float* x    = (const float*)d_in[0];
    const float* w    = (const float*)d_in[1];
    const float* rk   = (const float*)d_in[2];
    const float* bias = (const float*)d_in[3];
    float* out = (float*)d_out;

    char* ws = (char*)d_ws;
    const size_t XZ_BYTES   = (size_t)Bb * Tt * G4 * sizeof(_Float16);      // 268,435,456
    const size_t HBUF_BYTES = (size_t)2 * Bb * Hh * sizeof(unsigned short); // 262,144
    const size_t BAR_BYTES  = 2048;

    _Float16* xzh = (_Float16*)ws;
    unsigned* hbuf = (unsigned*)(ws + XZ_BYTES);
    unsigned* bar = (unsigned*)(ws + XZ_BYTES + HBUF_BYTES);

    hipMemsetAsync(ws + XZ_BYTES, 0, HBUF_BYTES + BAR_BYTES, stream);

    lstm_xz<<<dim3(8192), dim3(256), 0, stream>>>(x, w, bias, xzh);
    lstm_rec<<<dim3(128), dim3(256), 0, stream>>>(xzh, rk, hbuf, bar, out);
}

// Round 3
// 2202.636 us; speedup vs baseline: 1.8202x; 1.1467x over previous
//
#include <hip/hip_runtime.h>
#include <stdint.h>

// LSTM forward, B=128 T=512 F=256 H=512, Keras gate order i,f,g,o.
//  kernel lstm_xz : xz[B*T,2048] = x @ kernel + bias  (split-bf16 MFMA, fp16 output)
//  kernel lstm_rec: persistent scan. R3:
//    - SELF-SIGNALING h exchange: ring of 4 slots/group (512KB total), memset to
//      sentinel 0xFFFFFFFF (bf16 NaN pair; real h in (-1,1) can never encode it).
//      Producers fire-and-forget sc1 dword stores (NO vmcnt drain, NO flag).
//      Consumers poll the data: re-issue the 4 staging dwordx4 loads until no dword
//      is sentinel. Flag protocol deleted; signal+data = ONE LLC round trip.
//    - Slot recycle: at iter t, poll success on slot (t-1) proves all 16 blocks
//      consumed slot (t-2) -> each block re-sentinels its own 32-col region of
//      slot (t-2). Reuse at iter t+2; every block's poll vmcnt(0) (waits stores
//      too) orders reset-store before its later h-store. Deadlock-free.
//    - R (B-operand) fragments hoisted to REGISTERS once (128 VGPR/wave; 1 block/CU
//      so 512 VGPR/wave available). GEMM: 48 -> 16 ds_read_b128/wave; ~2/3 of LDS
//      bank conflicts and pipe pressure gone.
// ws layout: [0, 256MB) xz fp16 | hbuf 8 groups x 4 slots x 16 rows x 256 dwords (512KB)

#define Bb 128
#define Tt 512
#define Ff 256
#define Hh 512
#define G4 2048
#define SENT 0xFFFFFFFFu

typedef __attribute__((ext_vector_type(8))) short short8;
typedef __attribute__((ext_vector_type(4))) float floatx4;
typedef __attribute__((ext_vector_type(4))) unsigned int uint4v;

__device__ __forceinline__ unsigned short f2bf(float f) {
    unsigned u = __float_as_uint(f);
    return (unsigned short)((u + 0x7FFFu + ((u >> 16) & 1u)) >> 16);
}
__device__ __forceinline__ float bf2f(unsigned short h) {
    return __uint_as_float(((unsigned)h) << 16);
}
__device__ __forceinline__ float sigm(float x) { return 1.f / (1.f + __expf(-x)); }
__device__ __forceinline__ float tanh_f(float x) {
    float e = __expf(-2.f * fabsf(x));
    return copysignf((1.f - e) / (1.f + e), x);
}

// ---------------------------------------------------------------------------
// Kernel A: xz = x @ w + bias, stored fp16. Split-bf16 (x=hi+lo) for accuracy.
// 128x128 tile / block, BK=32 (orig k), K=256. Grid 8192 blocks. (unchanged)
// ---------------------------------------------------------------------------
__global__ __launch_bounds__(256, 2) void lstm_xz(
    const float* __restrict__ x, const float* __restrict__ w,
    const float* __restrict__ bias, _Float16* __restrict__ xzh)
{
    __shared__ unsigned short Ahi[128 * 40];
    __shared__ unsigned short Alo[128 * 40];
    __shared__ unsigned short Wt [128 * 40];

    const int tid = threadIdx.x;
    int idx = blockIdx.x;
    int xcd = idx & 7;
    int chunk = idx >> 3;
    int msup = chunk >> 7;
    int s = chunk & 127;
    int nt = s >> 3;
    int mi0 = s & 7;
    int mt = xcd * 64 + msup * 8 + mi0;
    const int m0 = mt << 7;
    const int n0 = nt << 7;

    const int lane = tid & 63;
    const int wv = tid >> 6;
    const int wm = wv >> 1, wn = wv & 1;
    const int cB = lane & 15, kgrp = lane >> 4;

    floatx4 acc[4][4];
#pragma unroll
    for (int i = 0; i < 4; ++i)
#pragma unroll
        for (int j = 0; j < 4; ++j) acc[i][j] = (floatx4){0.f, 0.f, 0.f, 0.f};

    float bv[4];
#pragma unroll
    for (int ni = 0; ni < 4; ++ni) bv[ni] = bias[n0 + wn * 64 + ni * 16 + cB];

    for (int it = 0; it < 8; ++it) {
        const int k0 = it * 32;
#pragma unroll
        for (int sw = 0; sw < 4; ++sw) {
            int e = sw * 256 + tid;
            int row = e >> 3, kq = e & 7;
            float4 v = *((const float4*)(x + (size_t)(m0 + row) * Ff + k0) + kq);
            unsigned short h0 = f2bf(v.x), h1 = f2bf(v.y), h2 = f2bf(v.z), h3 = f2bf(v.w);
            unsigned short l0 = f2bf(v.x - bf2f(h0)), l1 = f2bf(v.y - bf2f(h1));
            unsigned short l2 = f2bf(v.z - bf2f(h2)), l3 = f2bf(v.w - bf2f(h3));
            uint2 ph, pl;
            ph.x = (unsigned)h0 | ((unsigned)h1 << 16); ph.y = (unsigned)h2 | ((unsigned)h3 << 16);
            pl.x = (unsigned)l0 | ((unsigned)l1 << 16); pl.y = (unsigned)l2 | ((unsigned)l3 << 16);
            *(uint2*)(&Ahi[row * 40 + kq * 4]) = ph;
            *(uint2*)(&Alo[row * 40 + kq * 4]) = pl;
        }
#pragma unroll
        for (int sw = 0; sw < 4; ++sw) {
            int e = sw * 256 + tid;
            int kr = e >> 5, nq = e & 31;
            float4 v = *((const float4*)(w + (size_t)(k0 + kr) * G4 + n0) + nq);
            int nb = nq * 4;
            Wt[(nb + 0) * 40 + kr] = f2bf(v.x);
            Wt[(nb + 1) * 40 + kr] = f2bf(v.y);
            Wt[(nb + 2) * 40 + kr] = f2bf(v.z);
            Wt[(nb + 3) * 40 + kr] = f2bf(v.w);
        }
        __syncthreads();

        short8 bfr[4];
#pragma unroll
        for (int ni = 0; ni < 4; ++ni)
            bfr[ni] = *(const short8*)(&Wt[(wn * 64 + ni * 16 + cB) * 40 + kgrp * 8]);
#pragma unroll
        for (int mi = 0; mi < 4; ++mi) {
            short8 ah = *(const short8*)(&Ahi[(wm * 64 + mi * 16 + cB) * 40 + kgrp * 8]);
            short8 al = *(const short8*)(&Alo[(wm * 64 + mi * 16 + cB) * 40 + kgrp * 8]);
#pragma unroll
            for (int ni = 0; ni < 4; ++ni) {
                acc[mi][ni] = __builtin_amdgcn_mfma_f32_16x16x32_bf16(ah, bfr[ni], acc[mi][ni], 0, 0, 0);
                acc[mi][ni] = __builtin_amdgcn_mfma_f32_16x16x32_bf16(al, bfr[ni], acc[mi][ni], 0, 0, 0);
            }
        }
        __syncthreads();
    }
#pragma unroll
    for (int mi = 0; mi < 4; ++mi)
#pragma unroll
        for (int ni = 0; ni < 4; ++ni) {
            int rowb = m0 + wm * 64 + mi * 16 + kgrp * 4;
            int col = n0 + wn * 64 + ni * 16 + cB;
#pragma unroll
            for (int rr = 0; rr < 4; ++rr)
                xzh[(size_t)(rowb + rr) * G4 + col] = (_Float16)(acc[mi][ni][rr] + bv[ni]);
        }
}

// ---------------------------------------------------------------------------
// Kernel R: persistent scan, 128 blocks = 8 row-groups x 16 col-blocks.
// Block: 256 thr / 4 waves; wave w owns h cols [cb*32 + w*8, +8) (x 4 gates = 32 n).
// R fragments in registers; h tile [16][512] staged per step via sentinel-poll.
// ---------------------------------------------------------------------------
__global__ __launch_bounds__(256, 1) void lstm_rec(
    const _Float16* __restrict__ xzh, const float* __restrict__ rk,
    unsigned* __restrict__ hbuf_u, float* __restrict__ out)
{
    __shared__ unsigned short Rlds[128 * 512];   // 128 KB, staging for B-frag hoist
    __shared__ unsigned short hlds[16 * 512];    // 16 KB,  [row][k] swizzled

    const int tid = threadIdx.x;
    const int idx = blockIdx.x;
    const int rg = idx & 7;          // row group
    const int cb = idx >> 3;         // 0..15 col block
    const int b0 = rg * 16;
    const int hc0 = cb * 32;

    const int lane = tid & 63;
    const int wv = tid >> 6;
    const int cB = lane & 15, kgrp = lane >> 4;
    const int hcw = hc0 + wv * 8;    // wave's 8 h cols
    const int c7 = cB & 7;
    const int col = hcw + c7;        // this lane's h col (duplicated in lane^8)
    const bool hi = (cB & 8) != 0;

    // ---- preload R slice into LDS, bf16, XOR-swizzled: elem (n,k) at k^((n&7)*8) ----
    for (int e = tid; e < 64 * 512; e += 256) {
        int p = e & 63, k = e >> 6;
        int n0 = 2 * p;
        int loc = n0 & 31, w = n0 >> 5;
        int gate = ((loc >> 4) << 1) | ((loc >> 3) & 1);
        int gcol = gate * Hh + hc0 + w * 8 + (loc & 7);
        float2 v = *(const float2*)(rk + (size_t)k * G4 + gcol);
        Rlds[n0 * 512 + (k ^ ((n0 & 7) << 3))] = f2bf(v.x);
        Rlds[(n0 + 1) * 512 + (k ^ (((n0 + 1) & 7) << 3))] = f2bf(v.y);
    }

    // per-row running xz pointers (4), gate offset is an immediate (g*1KB)
    const unsigned* xz_u = (const unsigned*)xzh;
    const unsigned* pr[4];
#pragma unroll
    for (int r = 0; r < 4; ++r)
        pr[r] = xz_u + ((size_t)(b0 + kgrp * 4 + r) * Tt * G4 + (col & ~1)) / 2;

    float xzr[16];                            // [gate*4 + row]
#pragma unroll
    for (int g = 0; g < 4; ++g)
#pragma unroll
        for (int r = 0; r < 4; ++r) {
            unsigned v = pr[r][g * 256];
            xzr[g * 4 + r] = (float)__builtin_bit_cast(_Float16,
                (unsigned short)((col & 1) ? (v >> 16) : (v & 0xffffu)));
        }
#pragma unroll
    for (int r = 0; r < 4; ++r) pr[r] += G4 / 2;   // -> t=1

    __syncthreads();  // Rlds ready

    // ---- hoist B fragments to registers: 2 n-tiles x 16 kk = 128 VGPRs ----
    short8 bf0[16], bf1[16];
    {
        const int nb = wv * 32;
        const int swz = c7 << 3;
#pragma unroll
        for (int kk = 0; kk < 16; ++kk) {
            int kb = (kk * 32 + kgrp * 8) ^ swz;
            bf0[kk] = *(const short8*)&Rlds[(nb + cB) * 512 + kb];
            bf1[kk] = *(const short8*)&Rlds[(nb + 16 + cB) * 512 + kb];
        }
    }

    float creg[4] = {0.f, 0.f, 0.f, 0.f};
    unsigned* hlds_u = (unsigned*)hlds;
    unsigned* const gbase = hbuf_u + (size_t)rg * 4 * 4096;   // 4 slots x 16x256 dwords

    for (int t = 0; t < Tt; ++t) {
        const bool last = (t == Tt - 1);

        // 1. prefetch xz(t+1): HBM latency hides under poll+GEMM
        unsigned pf[16];
        if (!last) {
#pragma unroll
            for (int g = 0; g < 4; ++g)
#pragma unroll
                for (int r = 0; r < 4; ++r)
                    pf[g * 4 + r] = pr[r][g * 256];
        }

        floatx4 acc0 = (floatx4){0.f, 0.f, 0.f, 0.f};
        floatx4 acc1 = (floatx4){0.f, 0.f, 0.f, 0.f};

        if (t > 0) {
            // 2. self-signaling poll+stage of h(t-1), slot (t-1)&3:
            //    re-issue 4 pipelined dwordx4 sc1 loads until no dword is sentinel.
            const unsigned* sb = gbase + ((t - 1) & 3) * 4096;
            const unsigned* p0 = sb + (wv + 0) * 256 + 4 * lane;
            const unsigned* p1 = sb + (wv + 4) * 256 + 4 * lane;
            const unsigned* p2 = sb + (wv + 8) * 256 + 4 * lane;
            const unsigned* p3 = sb + (wv + 12) * 256 + 4 * lane;
            uint4v v0, v1, v2, v3;
            for (;;) {
                asm volatile("global_load_dwordx4 %0, %1, off sc0 sc1" : "=v"(v0) : "v"(p0) : "memory");
                asm volatile("global_load_dwordx4 %0, %1, off sc0 sc1" : "=v"(v1) : "v"(p1) : "memory");
                asm volatile("global_load_dwordx4 %0, %1, off sc0 sc1" : "=v"(v2) : "v"(p2) : "memory");
                asm volatile("global_load_dwordx4 %0, %1, off sc0 sc1" : "=v"(v3) : "v"(p3) : "memory");
                asm volatile("s_waitcnt vmcnt(0)" ::: "memory");
                bool bad = (v0[0] == SENT) | (v0[1] == SENT) | (v0[2] == SENT) | (v0[3] == SENT)
                         | (v1[0] == SENT) | (v1[1] == SENT) | (v1[2] == SENT) | (v1[3] == SENT)
                         | (v2[0] == SENT) | (v2[1] == SENT) | (v2[2] == SENT) | (v2[3] == SENT)
                         | (v3[0] == SENT) | (v3[1] == SENT) | (v3[2] == SENT) | (v3[3] == SENT);
                if (!bad) break;
            }
            __builtin_amdgcn_sched_barrier(0);
            *(uint4v*)(hlds_u + (wv + 0) * 256 + 4 * (lane ^ ((wv + 0) & 7))) = v0;
            *(uint4v*)(hlds_u + (wv + 4) * 256 + 4 * (lane ^ ((wv + 4) & 7))) = v1;
            *(uint4v*)(hlds_u + (wv + 8) * 256 + 4 * (lane ^ ((wv + 8) & 7))) = v2;
            *(uint4v*)(hlds_u + (wv + 12) * 256 + 4 * (lane ^ ((wv + 12) & 7))) = v3;
            __syncthreads();

            // 3. recycle slot (t-2)&3: poll success on (t-1) proves all 16 blocks
            //    consumed (t-2). Re-sentinel own 32-col region (1 dword/thread).
            //    Ordered before our own future h-store into this slot by the next
            //    iteration's poll vmcnt(0) (waits on stores too).
            if (t >= 2) {
                unsigned* rs = gbase + ((t - 2) & 3) * 4096
                             + (tid >> 4) * 256 + (hc0 >> 1) + (tid & 15);
                __hip_atomic_store(rs, SENT, __ATOMIC_RELAXED, __HIP_MEMORY_SCOPE_AGENT);
            }

            // 4. GEMM: 16 ds_read_b128 (A) + 32 MFMA, B from registers
            const int swz = c7 << 3;
#pragma unroll
            for (int kk = 0; kk < 16; ++kk) {
                int kb = (kk * 32 + kgrp * 8) ^ swz;
                short8 a = *(const short8*)&hlds[cB * 512 + kb];
                acc0 = __builtin_amdgcn_mfma_f32_16x16x32_bf16(a, bf0[kk], acc0, 0, 0, 0);
                acc1 = __builtin_amdgcn_mfma_f32_16x16x32_bf16(a, bf1[kk], acc1, 0, 0, 0);
            }
        }
        // t==0: h = 0 -> z = xz only (acc stays 0), no stage, no GEMM.

        // 5. elementwise, in-register. C layout: col=lane&15, row=kgrp*4+reg.
        float hv[4];
#pragma unroll
        for (int r = 0; r < 4; ++r) {
            float a0 = acc0[r], a1 = acc1[r];
            float a0x = __shfl_xor(a0, 8);
            float a1x = __shfl_xor(a1, 8);
            float zi = (hi ? a0x : a0) + xzr[0 * 4 + r];
            float zf = (hi ? a0 : a0x) + xzr[1 * 4 + r];
            float zg = (hi ? a1x : a1) + xzr[2 * 4 + r];
            float zo = (hi ? a1 : a1x) + xzr[3 * 4 + r];
            creg[r] = sigm(zf) * creg[r] + sigm(zi) * tanh_f(zg);
            hv[r] = sigm(zo) * tanh_f(creg[r]);
        }

        float hn[4];
#pragma unroll
        for (int r = 0; r < 4; ++r) hn[r] = __shfl_xor(hv[r], 1);
        const bool ew = (!hi && !(cB & 1));

        if (!last) {
            // 6. h exchange: fire-and-forget sc1 stores into slot t&3. The data IS
            //    the signal (sentinel-poll on consumer side). No vmcnt, no flag.
            unsigned* wbase = gbase + (t & 3) * 4096;
#pragma unroll
            for (int r = 0; r < 4; ++r) {
                if (ew) {
                    unsigned hp = (unsigned)f2bf(hv[r]) | ((unsigned)f2bf(hn[r]) << 16);
                    __hip_atomic_store(wbase + (kgrp * 4 + r) * 256 + (col >> 1), hp,
                                       __ATOMIC_RELAXED, __HIP_MEMORY_SCOPE_AGENT);
                }
            }
        }

        // 7. output stores (cached; off the producer->consumer chain)
#pragma unroll
        for (int r = 0; r < 4; ++r) {
            if (ew) {
                size_t b = (size_t)(b0 + kgrp * 4 + r);
                *(float2*)(out + (b * Tt + (size_t)t) * Hh + col) = make_float2(hv[r], hn[r]);
            }
        }

        if (last) {
            float* hl = out + (size_t)Bb * Tt * Hh;
            float* cl = hl + (size_t)Bb * Hh;
#pragma unroll
            for (int r = 0; r < 4; ++r) {
                float cn = __shfl_xor(creg[r], 1);
                if (ew) {
                    size_t b = (size_t)(b0 + kgrp * 4 + r);
                    *(float2*)(hl + b * Hh + col) = make_float2(hv[r], hn[r]);
                    *(float2*)(cl + b * Hh + col) = make_float2(creg[r], cn);
                }
            }
            break;
        }

        // 8. consume prefetched xz; advance row pointers
#pragma unroll
        for (int i = 0; i < 16; ++i)
            xzr[i] = (float)__builtin_bit_cast(_Float16,
                (unsigned short)((col & 1) ? (pf[i] >> 16) : (pf[i] & 0xffffu)));
#pragma unroll
        for (int r = 0; r < 4; ++r) pr[r] += G4 / 2;

        __syncthreads();   // protects hlds (all GEMM reads done before next restage)
    }
}

// ---------------------------------------------------------------------------
extern "C" void kernel_launch(void* const* d_in, const int* in_sizes, int n_in,
                              void* d_out, int out_size, void* d_ws, size_t ws_size,
                              hipStream_t stream) {
    (void)in_sizes; (void)n_in; (void)out_size; (void)ws_size;
    const float* x    = (const float*)d_in[0];
    const float* w    = (const float*)d_in[1];
    const float* rk   = (const float*)d_in[2];
    const float* bias = (const float*)d_in[3];
    float* out = (float*)d_out;

    char* ws = (char*)d_ws;
    const size_t XZ_BYTES   = (size_t)Bb * Tt * G4 * sizeof(_Float16);      // 268,435,456
    const size_t HBUF_BYTES = (size_t)8 * 4 * 16 * 256 * 4;                 // 524,288

    _Float16* xzh = (_Float16*)ws;
    unsigned* hbuf = (unsigned*)(ws + XZ_BYTES);

    // sentinel-init all slots (0xFF bytes -> 0xFFFFFFFF dwords)
    hipMemsetAsync(ws + XZ_BYTES, 0xFF, HBUF_BYTES, stream);

    lstm_xz<<<dim3(8192), dim3(256), 0, stream>>>(x, w, bias, xzh);
    lstm_rec<<<dim3(128), dim3(256), 0, stream>>>(xzh, rk, hbuf, out);
}